// Round 6
// baseline (577.971 us; speedup 1.0000x reference)
//
#include <hip/hip_runtime.h>

typedef unsigned short u16;
typedef unsigned int   u32;

#define EPSF 1e-5f

typedef __attribute__((ext_vector_type(8))) short bf16x8;
typedef __attribute__((ext_vector_type(4))) float f32x4;

__device__ __forceinline__ u16 f2us(float f){
  union { float f; u32 i; } v; v.f = f;
  u32 i = v.i;
  return (u16)((i + 0x7FFFu + ((i >> 16) & 1u)) >> 16);   // RNE f32->bf16
}
__device__ __forceinline__ float us2f(u16 u){
  union { u32 i; float f; } v; v.i = ((u32)u) << 16; return v.f;
}
__device__ __forceinline__ float hswish(float x){
  return x * fminf(fmaxf(x + 3.f, 0.f), 6.f) * (1.f/6.f);
}
__device__ __forceinline__ float sigm(float x){ return 1.f / (1.f + expf(-x)); }

// ---- workspace layout (fp32 elements) ----
#define WS_PARTIAL 0          // 512*3200 = 1638400 (reuses XV/XT/XS space, dead after k34)
#define WS_XV      0          // 1228800
#define WS_XT      1228800    // 102400
#define WS_XS      1331200    // 1331200
#define WS_GATE    2683200    // 1600
#define WS_ABN     2688384    // 1600
#define WS_BBN     2689984    // 1600
#define WS_P1B     2692096    // 4096*4 per-block BN partials (k1 -> k2)
#define WS_A2B     2708480    // 256*128 per-block stats partials (k2 -> k34)
#define WS_YWS     2741248    // 15360000 u32 slots (bf16 y, rotated; 3750 u32/row) — optional

// K1: per (n,c) slab: xv_pre[n,c,t], xt_pre[n,c,v]; per-block BN partials (non-atomic).
__global__ __launch_bounds__(256) void k1(const float* __restrict__ x0,
    const float* __restrict__ Wv, const float* __restrict__ bv,
    const float* __restrict__ Wt, const float* __restrict__ bt,
    float* __restrict__ ws)
{
  __shared__ float slab[7500];
  __shared__ float wvc[25];
  __shared__ float wts[300];
  __shared__ float colS[25];
  __shared__ float red[8];
  int blk = blockIdx.x;           // n*64 + c
  int c = blk & 63;
  int tid = threadIdx.x;
  const float4* src = (const float4*)(x0) + blk*1875;
  float4* dst = (float4*)slab;
  for (int i = tid; i < 1875; i += 256) dst[i] = src[i];
  int cm = c % 25;
  if (tid < 25){ wvc[tid] = Wv[(tid - cm + 25) % 25]; colS[tid] = 0.f; }
  for (int i = tid; i < 300; i += 256) wts[i] = Wt[i];
  __syncthreads();
  float bvf = bv[0];
  float s1 = 0.f, s2 = 0.f;
  float ca[25];
  #pragma unroll
  for (int u = 0; u < 25; u++) ca[u] = 0.f;
  for (int t = tid; t < 300; t += 256){
    const float* row = &slab[t*25];
    float wt = wts[t];
    float xv = bvf;
    #pragma unroll
    for (int u = 0; u < 25; u++){
      float xf = row[u];
      xv += wvc[u] * xf;
      ca[u] += wt * xf;
    }
    ws[WS_XV + blk*300 + t] = xv;
    s1 += xv; s2 += xv*xv;
  }
  #pragma unroll
  for (int off = 32; off >= 1; off >>= 1){
    s1 += __shfl_xor(s1, off);
    s2 += __shfl_xor(s2, off);
    #pragma unroll
    for (int u = 0; u < 25; u++) ca[u] += __shfl_xor(ca[u], off);
  }
  int lane = tid & 63, wvi = tid >> 6;
  if (lane == 0){
    #pragma unroll
    for (int u = 0; u < 25; u++) atomicAdd(&colS[u], ca[u]);
    red[wvi] = s1; red[4 + wvi] = s2;
  }
  __syncthreads();
  if (wvi == 0){
    float btf = bt[0];
    float val = 0.f;
    if (lane < 25){
      val = colS[(lane + cm) % 25] + btf;
      ws[WS_XT + blk*25 + lane] = val;
    }
    float t1 = val, t2 = val*val;
    #pragma unroll
    for (int off = 32; off >= 1; off >>= 1){ t1 += __shfl_xor(t1, off); t2 += __shfl_xor(t2, off); }
    if (lane == 0){
      float4 pv;
      pv.x = red[0]+red[1]+red[2]+red[3];
      pv.y = red[4]+red[5]+red[6]+red[7];
      pv.z = t1; pv.w = t2;
      *(float4*)&ws[WS_P1B + blk*4] = pv;
    }
  }
}

// K2: prologue reduces P1B -> bn params; GEMM -> XS; per-block stats partials to A2B.
__global__ __launch_bounds__(256) void k2(
    const float* __restrict__ Ws_, const float* __restrict__ gv, const float* __restrict__ bev,
    const float* __restrict__ gt, const float* __restrict__ bet,
    float* __restrict__ ws)
{
  __shared__ float xsc[64*82];
  __shared__ float wsl[64*65];
  __shared__ float accs[128];
  __shared__ float bnp[4];
  __shared__ float pr[4][4];
  int tid = threadIdx.x;
  int n = blockIdx.x >> 2;
  int chunk = blockIdx.x & 3;
  int l0 = chunk * 82;
  int cw = (325 - l0 < 82) ? (325 - l0) : 82;
  // reduce per-block BN partials (4096 x float4)
  {
    float4 acc = {0.f,0.f,0.f,0.f};
    const float4* p4 = (const float4*)&ws[WS_P1B];
    for (int b = tid; b < 4096; b += 256){
      float4 v = p4[b];
      acc.x += v.x; acc.y += v.y; acc.z += v.z; acc.w += v.w;
    }
    #pragma unroll
    for (int off = 32; off >= 1; off >>= 1){
      acc.x += __shfl_xor(acc.x, off); acc.y += __shfl_xor(acc.y, off);
      acc.z += __shfl_xor(acc.z, off); acc.w += __shfl_xor(acc.w, off);
    }
    int lane = tid & 63, wv = tid >> 6;
    if (lane == 0){ pr[wv][0] = acc.x; pr[wv][1] = acc.y; pr[wv][2] = acc.z; pr[wv][3] = acc.w; }
  }
  for (int i = tid; i < 4096; i += 256){
    int o = i >> 6, cc = i & 63;
    wsl[o*65 + cc] = Ws_[i];
  }
  if (tid < 128) accs[tid] = 0.f;
  __syncthreads();
  if (tid == 0){
    float p0 = pr[0][0]+pr[1][0]+pr[2][0]+pr[3][0];
    float p1 = pr[0][1]+pr[1][1]+pr[2][1]+pr[3][1];
    float p2 = pr[0][2]+pr[1][2]+pr[2][2]+pr[3][2];
    float p3 = pr[0][3]+pr[1][3]+pr[2][3]+pr[3][3];
    float Mv = 1228800.f;
    float mv = p0 / Mv;
    float varv = p1 / Mv - mv*mv;
    float av = gv[0] * rsqrtf(varv + EPSF);
    bnp[0] = av; bnp[1] = bev[0] - mv*av;
    float Mt = 102400.f;
    float mt = p2 / Mt;
    float vart = p3 / Mt - mt*mt;
    float at = gt[0] * rsqrtf(vart + EPSF);
    bnp[2] = at; bnp[3] = bet[0] - mt*at;
  }
  __syncthreads();
  float a_v = bnp[0], b_v = bnp[1], a_t = bnp[2], b_t = bnp[3];
  for (int i = tid; i < 64*cw; i += 256){
    int ch = i / cw, li = i - ch*cw;
    int f = ch*325 + l0 + li;
    float e;
    if (f < 1600) e = ws[WS_XT + n*1600 + f] * a_t + b_t;
    else          e = ws[WS_XV + n*19200 + (f - 1600)] * a_v + b_v;
    xsc[ch*82 + li] = hswish(e);
  }
  __syncthreads();
  int o = tid & 63;
  float s1 = 0.f, s2 = 0.f;
  for (int i = tid; i < 64*cw; i += 256){
    int li = i >> 6;
    float acc = 0.f;
    #pragma unroll 8
    for (int cc = 0; cc < 64; cc++)
      acc += wsl[o*65 + cc] * xsc[cc*82 + li];
    ws[WS_XS + (n*64 + o)*325 + l0 + li] = acc;
    s1 += acc; s2 += acc*acc;
  }
  atomicAdd(&accs[o*2+0], s1);
  atomicAdd(&accs[o*2+1], s2);
  __syncthreads();
  if (tid < 128) ws[WS_A2B + blockIdx.x*128 + tid] = accs[tid];
}

// K34: fused k3+k4. 13 blocks: 0..11 = t-tiles of 25 (out2), 12 = v-tile (gate).
// Prologue reduces A2B -> per-d BN params; n-sum of hswish(bn(xs)) into LDS S-tile;
// then the small GEMM.
__global__ __launch_bounds__(256) void k34(const float* __restrict__ gs, const float* __restrict__ bes,
    const float* __restrict__ Wt2, const float* __restrict__ bt2,
    const float* __restrict__ Wv2, const float* __restrict__ bv2,
    float* __restrict__ out2, float* __restrict__ ws)
{
  __shared__ float a2r[256];
  __shared__ float w2[4096];
  __shared__ float aS[64], bS[64];
  __shared__ float Sl[64*26];
  int tid = threadIdx.x;
  bool isV = (blockIdx.x == 12);
  int t0 = blockIdx.x * 25;
  // reduce stats partials: 256 k2-blocks x 128
  {
    int j = tid & 127, h = tid >> 7;
    float s = 0.f;
    #pragma unroll 8
    for (int b = h*128; b < h*128 + 128; ++b)
      s += ws[WS_A2B + b*128 + j];
    a2r[h*128 + j] = s;
  }
  const float* Wsel = isV ? Wv2 : Wt2;
  for (int i = tid; i < 4096; i += 256) w2[i] = Wsel[i];
  __syncthreads();
  if (tid < 64){
    float s1 = a2r[2*tid]   + a2r[128 + 2*tid];
    float s2 = a2r[2*tid+1] + a2r[128 + 2*tid+1];
    float m = s1 / 20800.f;
    float var = s2 / 20800.f - m*m;
    float a = gs[tid] * rsqrtf(var + EPSF);
    aS[tid] = a; bS[tid] = bes[tid] - m*a;
  }
  __syncthreads();
  // accumulate S-tile over n (7 register slots per thread)
  int offk[7]; float ak[7], bk[7]; int dk_[7], tk_[7]; bool vk[7];
  #pragma unroll
  for (int k = 0; k < 7; k++){
    int i = tid + 256*k;
    vk[k] = (i < 1600);
    if (vk[k]){
      int dd = i / 25, tt = i - dd*25;
      dk_[k] = dd; tk_[k] = tt;
      offk[k] = dd*325 + (isV ? (300 + tt) : (t0 + tt));
      ak[k] = aS[dd]; bk[k] = bS[dd];
    }
  }
  float acc[7];
  #pragma unroll
  for (int k = 0; k < 7; k++) acc[k] = 0.f;
  for (int n = 0; n < 64; ++n){
    const float* base = ws + WS_XS + n*20800;
    #pragma unroll
    for (int k = 0; k < 7; k++)
      if (vk[k]) acc[k] += hswish(ak[k]*base[offk[k]] + bk[k]);
  }
  #pragma unroll
  for (int k = 0; k < 7; k++)
    if (vk[k]) Sl[dk_[k]*26 + tk_[k]] = acc[k];
  __syncthreads();
  // small GEMM over d
  int o = tid & 63, tq = tid >> 6;
  float bias = isV ? bv2[o] : bt2[o];
  for (int tv = tq; tv < 25; tv += 4){
    float s = 0.f;
    #pragma unroll 8
    for (int d = 0; d < 64; ++d)
      s += w2[o*64 + d] * Sl[d*26 + tv];
    float val = sigm(s * (1.f/64.f) + bias);
    if (isV) ws[WS_GATE + tv*64 + o] = tanhf(val) + 1.f;
    else     out2[o*300 + t0 + tv] = val;
  }
}

// K5y: single GEMM pass: stats (reg accumulators -> colacc -> private partials)
// AND (if storeY) writes rotated bf16 y to WS_YWS (3750 u32/row) via in-LDS scatter.
__global__ __launch_bounds__(512, 2) void k5y(const float* __restrict__ x0,
    const float* __restrict__ Lw, float* __restrict__ ws, const int storeY)
{
  __shared__ u16 xraw[64*154];
  __shared__ u16 zsh[160*72];
  __shared__ u16 lwt[64*72];
  __shared__ float gate[1600];
  __shared__ float colacc[3300];
  int tid = threadIdx.x;
  int n = blockIdx.x >> 3, e8 = blockIdx.x & 7;
  int c0 = (e8*50) >> 3, c1 = ((e8+1)*50) >> 3;   // 6 or 7 chunks of 6 t-steps
  const float2* xsrc = (const float2*)x0;
  u32* yws = (u32*)(ws + WS_YWS);

  for (int i = tid; i < 1600; i += 512) gate[i] = ws[WS_GATE + i];
  for (int i = tid; i < 4096; i += 512){
    int c = i >> 6, d = i & 63;                    // coalesced Lw read
    lwt[d*72 + c] = f2us(Lw[c*64 + d]);
  }
  for (int i = tid; i < 3300; i += 512) colacc[i] = 0.f;
  for (int i = tid; i < 640; i += 512){ int c = i & 63, r = 150 + (i >> 6); zsh[r*72 + c] = 0; }
  // stage first chunk
  for (int i = tid; i < 4800; i += 512){
    int c = i / 75, j = i - c*75;
    float2 xy = xsrc[(n*64 + c)*3750 + c0*75 + j];
    *(u32*)&xraw[c*154 + 2*j] = (u32)f2us(xy.x) | ((u32)f2us(xy.y) << 16);
  }

  // --- chunk-invariant gather slots (pairs of adjacent c): packed src + gate offset ---
  u32 gsrc[10]; int gadr[10];
  #pragma unroll
  for (int k = 0; k < 10; k++){
    int p = tid + k*512;
    if (k < 9 || p < 4800){
      int cp = (p & 31)*2, r = p >> 5;
      int v = r - 25*((r*41) >> 10);                // r % 25, r < 160
      int base = r - v;
      int w = v + cp;
      int u1 = w - 25*((w*41) >> 10);               // (v+cp) % 25, w < 88
      int w2 = w + 1;
      int u2 = w2 - 25*((w2*41) >> 10);
      gsrc[k] = (u32)(cp*154 + base + u1) | ((u32)((cp+1)*154 + base + u2) << 16);
      gadr[k] = v*64 + cp;
    }
  }

  int lane = tid & 63, wvi = tid >> 6;
  int m16 = lane & 15, kq = lane >> 4;
  int dd = (wvi & 3)*16 + m16;

  // --- chunk-invariant scatter slots: xraw idx (0xFFFF sentinel for pad rows) ---
  u32 eidx[20];
  #pragma unroll
  for (int it = 0; it < 5; it++){
    int T = wvi + it*8;
    int r0 = (T >> 2) * 16;
    #pragma unroll
    for (int q = 0; q < 4; q++){
      int r = r0 + kq*4 + q;
      u32 e = 0xFFFFu;
      if (r < 150){
        int v = r - 25*((r*41) >> 10);
        int w = v + dd;
        int u = w - 25*((w*41) >> 10);
        e = (u32)(dd*154 + (r - v) + u);
      }
      eidx[it*4 + q] = e;
    }
  }

  bf16x8 b0, b1;
  float s_acc[20], q_acc[20];
  #pragma unroll
  for (int z = 0; z < 20; z++){ s_acc[z] = 0.f; q_acc[z] = 0.f; }

  for (int cc = c0; cc < c1; cc++){
    __syncthreads();                                // xraw ready
    #pragma unroll
    for (int k = 0; k < 10; k++){
      if (k < 9 || tid < 192){
        int p = tid + k*512;
        int dst = (p >> 5)*72 + (p & 31)*2;
        float gA = gate[gadr[k]];
        float gB = gate[gadr[k] + 1];
        u16 x1 = xraw[gsrc[k] & 0xFFFFu];
        u16 x2 = xraw[gsrc[k] >> 16];
        u32 pk = (u32)f2us(us2f(x1)*gA) | ((u32)f2us(us2f(x2)*gB) << 16);
        *(u32*)&zsh[dst] = pk;
      }
    }
    __syncthreads();                                // zsh ready, xraw gather-reads done
    if (cc == c0){
      b0 = *(const bf16x8*)&lwt[dd*72 + kq*8];
      b1 = *(const bf16x8*)&lwt[dd*72 + 32 + kq*8];
    }
    // prefetch next chunk into regs
    float2 pf[10];
    bool has = (cc + 1 < c1);
    if (has){
      #pragma unroll
      for (int k = 0; k < 10; k++){
        int i = tid + k*512;
        if (i < 4800){
          int c = i / 75, j = i - c*75;
          pf[k] = xsrc[(n*64 + c)*3750 + (cc+1)*75 + j];
        }
      }
    }
    f32x4 acc[5];
    #pragma unroll
    for (int it = 0; it < 5; it++){
      int T = wvi + it*8;
      int r0 = (T >> 2) * 16;
      bf16x8 a0 = *(const bf16x8*)&zsh[(r0 + m16)*72 + kq*8];
      bf16x8 a1 = *(const bf16x8*)&zsh[(r0 + m16)*72 + 32 + kq*8];
      f32x4 a = {0.f,0.f,0.f,0.f};
      a = __builtin_amdgcn_mfma_f32_16x16x32_bf16(a0, b0, a, 0, 0, 0);
      a = __builtin_amdgcn_mfma_f32_16x16x32_bf16(a1, b1, a, 0, 0, 0);
      acc[it] = a;
      // stats: pad rows contribute exactly 0
      #pragma unroll
      for (int q = 0; q < 4; q++){
        float y = a[q];
        s_acc[it*4 + q] += y;
        q_acc[it*4 + q] += y*y;
      }
    }
    if (storeY){
      // scatter rotated y into xraw (input no longer needed this chunk)
      #pragma unroll
      for (int s = 0; s < 20; s++){
        u32 e = eidx[s];
        if (e != 0xFFFFu) xraw[e] = f2us(acc[s>>2][s&3]);
      }
      __syncthreads();                              // scatter done
      for (int i = tid; i < 4800; i += 512){
        int d = i / 75, j = i - d*75;
        yws[(n*64 + d)*3750 + cc*75 + j] = *(const u32*)&xraw[d*154 + 2*j];
      }
    }
    __syncthreads();                                // xraw free for prefetch write
    if (has){
      #pragma unroll
      for (int k = 0; k < 10; k++){
        int i = tid + k*512;
        if (i < 4800){
          int c = i / 75, j = i - c*75;
          *(u32*)&xraw[c*154 + 2*j] = (u32)f2us(pf[k].x) | ((u32)f2us(pf[k].y) << 16);
        }
      }
    }
  }
  // one-time flush of register accumulators into LDS
  #pragma unroll
  for (int it = 0; it < 5; it++){
    int T = wvi + it*8;
    int r0 = (T >> 2) * 16;
    #pragma unroll
    for (int q = 0; q < 4; q++){
      int r = r0 + kq*4 + q;
      if (r < 150){
        int v = r - 25*((r*41) >> 10);              // r % 25, valid r<160
        atomicAdd(&colacc[v*66 + dd], s_acc[it*4 + q]);
        atomicAdd(&colacc[1650 + v*66 + dd], q_acc[it*4 + q]);
      }
    }
  }
  __syncthreads();
  // non-atomic private partial slice (coalesced)
  float* dst = ws + WS_PARTIAL + blockIdx.x*3200;
  for (int i = tid; i < 3200; i += 512){
    int f = (i < 1600) ? i : (i - 1600);
    int v = f >> 6, d = f & 63;
    dst[i] = colacc[((i < 1600) ? 0 : 1650) + v*66 + d];
  }
}

// K5ab: reduce 512 partial slices AND fold gbn/bbn into per-column affine a,b.
// 25 blocks; block b owns f = b*64 + (0..63), i.e. v = b, d = 0..63.
// rot=1: store at rotated column (vi*64+d) for streaming k6n; rot=0: at v*64+d for fallback k6.
__global__ __launch_bounds__(256) void k5ab(const float* __restrict__ gbn, const float* __restrict__ bbn,
                                            float* __restrict__ ws, const int rot)
{
  __shared__ float rs[4][64];
  __shared__ float rq[4][64];
  int tid = threadIdx.x;
  int fo = tid & 63, g = tid >> 6;
  int f = blockIdx.x*64 + fo;
  const float* src = ws + WS_PARTIAL;
  float s = 0.f, q = 0.f;
  #pragma unroll 8
  for (int b = g*128; b < g*128 + 128; ++b){
    s += src[b*3200 + f];
    q += src[b*3200 + 1600 + f];
  }
  rs[g][fo] = s; rq[g][fo] = q;
  __syncthreads();
  if (tid < 64){
    int d = tid, v = blockIdx.x;
    float S = rs[0][d] + rs[1][d] + rs[2][d] + rs[3][d];
    float Q = rq[0][d] + rq[1][d] + rq[2][d] + rq[3][d];
    float m = S / 19200.f;
    float var = Q / 19200.f - m*m;
    float rsq = rsqrtf(var + EPSF);
    int vi = (v + d) % 25;
    int fi = vi*64 + d;
    float a = gbn[fi] * rsq;
    int o = rot ? (vi*64 + d) : (v*64 + d);
    ws[WS_ABN + o] = a;
    ws[WS_BBN + o] = bbn[fi] - m*a;
  }
}

// K6n: streaming finale: out = relu(bf16(y)*A[u,d] + B[u,d] + x0). 4096 blocks = (n,d) rows.
// float4/uint2 vectorized; u-index incremental (1024 = -1 mod 25), no runtime div in loop.
__global__ __launch_bounds__(256) void k6n(const float* __restrict__ x0,
    float* __restrict__ out, const float* __restrict__ ws)
{
  __shared__ float sA2[28];
  __shared__ float sB2[28];
  int row = blockIdx.x;                             // n*64 + d
  int d = row & 63;
  int tid = threadIdx.x;
  if (tid < 28){
    int um = (tid >= 25) ? (tid - 25) : tid;
    sA2[tid] = ws[WS_ABN + um*64 + d];
    sB2[tid] = ws[WS_BBN + um*64 + d];
  }
  __syncthreads();
  const uint2*  yrow = (const uint2*)((const u32*)(ws + WS_YWS) + row*3750);
  const float4* xrow = (const float4*)x0 + row*1875;
  float4*       orow = (float4*)out + row*1875;
  int u = (4*tid) % 25;
  for (int j = tid; j < 1875; j += 256){
    uint2 yp = yrow[j];
    float4 x = xrow[j];
    float4 o;
    o.x = fmaxf(us2f((u16)(yp.x & 0xFFFFu)) * sA2[u]   + sB2[u]   + x.x, 0.f);
    o.y = fmaxf(us2f((u16)(yp.x >> 16))     * sA2[u+1] + sB2[u+1] + x.y, 0.f);
    o.z = fmaxf(us2f((u16)(yp.y & 0xFFFFu)) * sA2[u+2] + sB2[u+2] + x.z, 0.f);
    o.w = fmaxf(us2f((u16)(yp.y >> 16))     * sA2[u+3] + sB2[u+3] + x.w, 0.f);
    orow[j] = o;
    u = (u == 0) ? 24 : (u - 1);                    // +1024 elems = -1 mod 25
  }
}

// K6 (fallback, only if workspace too small for y-store): GEMM apply pass.
__global__ __launch_bounds__(512, 2) void k6(const float* __restrict__ x0,
    const float* __restrict__ Lw, float* __restrict__ out, float* __restrict__ ws)
{
  __shared__ u16 xraw[64*154];
  __shared__ u16 zsh[160*72];
  __shared__ u16 lwt[64*72];
  __shared__ float gate[1600];
  __shared__ float affA[1650];
  __shared__ float affB[1650];
  int tid = threadIdx.x;
  int n = blockIdx.x >> 3, e8 = blockIdx.x & 7;
  int c0 = (e8*50) >> 3, c1 = ((e8+1)*50) >> 3;
  const float2* xsrc = (const float2*)x0;

  for (int i = tid; i < 1600; i += 512){
    gate[i] = ws[WS_GATE + i];
    int v = i >> 6, d = i & 63;
    affA[v*66 + d] = ws[WS_ABN + i];
    affB[v*66 + d] = ws[WS_BBN + i];
  }
  for (int i = tid; i < 4096; i += 512){
    int c = i >> 6, d = i & 63;
    lwt[d*72 + c] = f2us(Lw[c*64 + d]);
  }
  for (int i = tid; i < 640; i += 512){ int c = i & 63, r = 150 + (i >> 6); zsh[r*72 + c] = 0; }
  for (int i = tid; i < 4800; i += 512){
    int c = i / 75, j = i - c*75;
    float2 xy = xsrc[(n*64 + c)*3750 + c0*75 + j];
    *(u32*)&xraw[c*154 + 2*j] = (u32)f2us(xy.x) | ((u32)f2us(xy.y) << 16);
  }

  u32 gsrc[10]; int gadr[10];
  #pragma unroll
  for (int k = 0; k < 10; k++){
    int p = tid + k*512;
    if (k < 9 || p < 4800){
      int cp = (p & 31)*2, r = p >> 5;
      int v = r - 25*((r*41) >> 10);
      int base = r - v;
      int w = v + cp;
      int u1 = w - 25*((w*41) >> 10);
      int w2 = w + 1;
      int u2 = w2 - 25*((w2*41) >> 10);
      gsrc[k] = (u32)(cp*154 + base + u1) | ((u32)((cp+1)*154 + base + u2) << 16);
      gadr[k] = v*64 + cp;
    }
  }

  int lane = tid & 63, wvi = tid >> 6;
  int m16 = lane & 15, kq = lane >> 4;
  int dd = (wvi & 3)*16 + m16;

  u32 eidx[20];
  #pragma unroll
  for (int it = 0; it < 5; it++){
    int T = wvi + it*8;
    int r0 = (T >> 2) * 16;
    #pragma unroll
    for (int q = 0; q < 4; q++){
      int r = r0 + kq*4 + q;
      u32 e = 0xFFFFu;
      if (r < 150){
        int v = r - 25*((r*41) >> 10);
        int w = v + dd;
        int u = w - 25*((w*41) >> 10);
        e = (u32)(dd*154 + (r - v) + u) | ((u32)(v*66 + dd) << 16);
      }
      eidx[it*4 + q] = e;
    }
  }

  bf16x8 b0, b1;

  for (int cc = c0; cc < c1; cc++){
    __syncthreads();
    #pragma unroll
    for (int k = 0; k < 10; k++){
      if (k < 9 || tid < 192){
        int p = tid + k*512;
        int dst = (p >> 5)*72 + (p & 31)*2;
        float gA = gate[gadr[k]];
        float gB = gate[gadr[k] + 1];
        u16 x1 = xraw[gsrc[k] & 0xFFFFu];
        u16 x2 = xraw[gsrc[k] >> 16];
        u32 pk = (u32)f2us(us2f(x1)*gA) | ((u32)f2us(us2f(x2)*gB) << 16);
        *(u32*)&zsh[dst] = pk;
      }
    }
    __syncthreads();
    if (cc == c0){
      b0 = *(const bf16x8*)&lwt[dd*72 + kq*8];
      b1 = *(const bf16x8*)&lwt[dd*72 + 32 + kq*8];
    }
    float2 pf[10];
    bool has = (cc + 1 < c1);
    if (has){
      #pragma unroll
      for (int k = 0; k < 10; k++){
        int i = tid + k*512;
        if (i < 4800){
          int c = i / 75, j = i - c*75;
          pf[k] = xsrc[(n*64 + c)*3750 + (cc+1)*75 + j];
        }
      }
    }
    f32x4 acc[5];
    #pragma unroll
    for (int it = 0; it < 5; it++){
      int T = wvi + it*8;
      int r0 = (T >> 2) * 16;
      bf16x8 a0 = *(const bf16x8*)&zsh[(r0 + m16)*72 + kq*8];
      bf16x8 a1 = *(const bf16x8*)&zsh[(r0 + m16)*72 + 32 + kq*8];
      f32x4 a = {0.f,0.f,0.f,0.f};
      a = __builtin_amdgcn_mfma_f32_16x16x32_bf16(a0, b0, a, 0, 0, 0);
      a = __builtin_amdgcn_mfma_f32_16x16x32_bf16(a1, b1, a, 0, 0, 0);
      acc[it] = a;
    }
    #pragma unroll
    for (int s = 0; s < 20; s++){
      u32 e = eidx[s];
      if ((e & 0xFFFFu) != 0xFFFFu){
        int idx = (int)(e & 0xFFFFu), ao = (int)(e >> 16);
        float resid = us2f(xraw[idx]);
        float val = acc[s>>2][s&3] * affA[ao] + affB[ao] + resid;
        xraw[idx] = f2us(fmaxf(val, 0.f));
      }
    }
    __syncthreads();
    for (int i = tid; i < 4800; i += 512){
      int d = i / 75, j = i - d*75;
      u32 pk = *(const u32*)&xraw[d*154 + 2*j];
      float2 o; o.x = us2f((u16)(pk & 0xFFFFu)); o.y = us2f((u16)(pk >> 16));
      ((float2*)out)[(n*64 + d)*3750 + cc*75 + j] = o;
    }
    __syncthreads();
    if (has){
      #pragma unroll
      for (int k = 0; k < 10; k++){
        int i = tid + k*512;
        if (i < 4800){
          int c = i / 75, j = i - c*75;
          *(u32*)&xraw[c*154 + 2*j] = (u32)f2us(pf[k].x) | ((u32)f2us(pf[k].y) << 16);
        }
      }
    }
  }
}

extern "C" void kernel_launch(void* const* d_in, const int* in_sizes, int n_in,
                              void* d_out, int out_size, void* d_ws, size_t ws_size,
                              hipStream_t stream)
{
  const float* x0  = (const float*)d_in[0];
  // d_in[1] shift_in, d_in[2] shift_out: closed-form rotations used instead
  const float* Wv  = (const float*)d_in[3];
  const float* bv  = (const float*)d_in[4];
  const float* gv  = (const float*)d_in[5];
  const float* bev = (const float*)d_in[6];
  const float* Wt  = (const float*)d_in[7];
  const float* bt  = (const float*)d_in[8];
  const float* gt  = (const float*)d_in[9];
  const float* bet = (const float*)d_in[10];
  const float* Ws_ = (const float*)d_in[11];
  // d_in[12] bs: cancels exactly in BN — dropped
  const float* gs  = (const float*)d_in[13];
  const float* bes = (const float*)d_in[14];
  const float* Wv2 = (const float*)d_in[15];
  const float* bv2 = (const float*)d_in[16];
  const float* Wt2 = (const float*)d_in[17];
  const float* bt2 = (const float*)d_in[18];
  const float* Lw  = (const float*)d_in[19];
  // d_in[20] Lb: cancels exactly in final BN — dropped
  const float* gbn = (const float*)d_in[21];
  const float* bbn = (const float*)d_in[22];
  float* out = (float*)d_out;
  float* ws = (float*)d_ws;

  const int big = (ws_size >= (size_t)(WS_YWS + 15360000) * 4) ? 1 : 0;

  k1<<<dim3(4096), dim3(256), 0, stream>>>(x0, Wv, bv, Wt, bt, ws);
  k2<<<dim3(256), dim3(256), 0, stream>>>(Ws_, gv, bev, gt, bet, ws);
  k34<<<dim3(13), dim3(256), 0, stream>>>(gs, bes, Wt2, bt2, Wv2, bv2, out + 30720000, ws);
  k5y<<<dim3(512), dim3(512), 0, stream>>>(x0, Lw, ws, big);
  k5ab<<<dim3(25), dim3(256), 0, stream>>>(gbn, bbn, ws, big);
  if (big){
    k6n<<<dim3(4096), dim3(256), 0, stream>>>(x0, out, ws);
  } else {
    k6<<<dim3(512), dim3(512), 0, stream>>>(x0, Lw, out, ws);
  }
}

// Round 7
// 460.584 us; speedup vs baseline: 1.2549x; 1.2549x over previous
//
#include <hip/hip_runtime.h>

typedef unsigned short u16;
typedef unsigned int   u32;

#define EPSF 1e-5f

typedef __attribute__((ext_vector_type(8))) short bf16x8;
typedef __attribute__((ext_vector_type(4))) float f32x4;

__device__ __forceinline__ u16 f2us(float f){
  union { float f; u32 i; } v; v.f = f;
  u32 i = v.i;
  return (u16)((i + 0x7FFFu + ((i >> 16) & 1u)) >> 16);   // RNE f32->bf16
}
__device__ __forceinline__ float us2f(u16 u){
  union { u32 i; float f; } v; v.i = ((u32)u) << 16; return v.f;
}
__device__ __forceinline__ float hswish(float x){
  return x * fminf(fmaxf(x + 3.f, 0.f), 6.f) * (1.f/6.f);
}
__device__ __forceinline__ float sigm(float x){ return 1.f / (1.f + expf(-x)); }

// ---- workspace layout (fp32 elements) ----
#define WS_SP      0          // 8*20800 k3p partials (overlays XV, dead after k2)
#define WS_PARTIAL 0          // 512*3200 k5y partials (overlays XV/SP, dead after k4r)
#define WS_XV      0          // 1228800
#define WS_XT      1228800    // 102400
#define WS_XS      1331200    // 1331200
#define WS_S       2662400    // 20800
#define WS_GATE    2683200    // 1600
#define WS_ABN     2688384    // 1600
#define WS_BBN     2689984    // 1600
#define WS_P1B     2692096    // 4096*4 per-block BN partials (k1 -> k2)
#define WS_A2B     2708480    // 256*128 per-block stats partials (k2 -> k3p)
#define WS_YWS     2741248    // 15360000 u32 slots (bf16 y, rotated; 3750 u32/row) — optional

// K1: per (n,c) slab: xv_pre[n,c,t], xt_pre[n,c,v]; per-block BN partials (non-atomic).
// xt column-sums computed by a direct (u, t-chunk) pass — no 25-register butterfly.
__global__ __launch_bounds__(256) void k1(const float* __restrict__ x0,
    const float* __restrict__ Wv, const float* __restrict__ bv,
    const float* __restrict__ Wt, const float* __restrict__ bt,
    float* __restrict__ ws)
{
  __shared__ float slab[7500];
  __shared__ float wvc[25];
  __shared__ float wts[300];
  __shared__ float ctp[200];
  __shared__ float red[8];
  int blk = blockIdx.x;           // n*64 + c
  int c = blk & 63;
  int tid = threadIdx.x;
  const float4* src = (const float4*)(x0) + blk*1875;
  float4* dst = (float4*)slab;
  for (int i = tid; i < 1875; i += 256) dst[i] = src[i];
  int cm = c % 25;
  if (tid < 25) wvc[tid] = Wv[(tid - cm + 25) % 25];
  for (int i = tid; i < 300; i += 256) wts[i] = Wt[i];
  __syncthreads();
  float bvf = bv[0];
  float s1 = 0.f, s2 = 0.f;
  for (int t = tid; t < 300; t += 256){
    const float* row = &slab[t*25];
    float xv = bvf;
    #pragma unroll
    for (int u = 0; u < 25; u++) xv += wvc[u] * row[u];
    ws[WS_XV + blk*300 + t] = xv;
    s1 += xv; s2 += xv*xv;
  }
  #pragma unroll
  for (int off = 32; off >= 1; off >>= 1){
    s1 += __shfl_xor(s1, off);
    s2 += __shfl_xor(s2, off);
  }
  int lane = tid & 63, wvi = tid >> 6;
  if (lane == 0){ red[wvi] = s1; red[4 + wvi] = s2; }
  // xt partials: 25 u x 8 t-chunks
  if (tid < 200){
    int u = tid >> 3, cch = tid & 7;
    int t0 = cch*38, t1 = (t0 + 38 < 300) ? (t0 + 38) : 300;
    float p = 0.f;
    for (int t = t0; t < t1; t++) p += wts[t] * slab[t*25 + u];
    ctp[tid] = p;                                 // ctp[u*8 + cch]
  }
  __syncthreads();
  if (wvi == 0){
    float btf = bt[0];
    float val = 0.f;
    if (lane < 25){
      int u = (lane + cm) % 25;
      float ct = 0.f;
      #pragma unroll
      for (int k = 0; k < 8; k++) ct += ctp[u*8 + k];
      val = ct + btf;
      ws[WS_XT + blk*25 + lane] = val;
    }
    float t1v = val, t2v = val*val;
    #pragma unroll
    for (int off = 32; off >= 1; off >>= 1){ t1v += __shfl_xor(t1v, off); t2v += __shfl_xor(t2v, off); }
    if (lane == 0){
      float4 pv;
      pv.x = red[0]+red[1]+red[2]+red[3];
      pv.y = red[4]+red[5]+red[6]+red[7];
      pv.z = t1v; pv.w = t2v;
      *(float4*)&ws[WS_P1B + blk*4] = pv;
    }
  }
}

// K2: prologue reduces P1B -> bn params; GEMM -> XS; per-block stats partials to A2B.
// Ws row in 16 float4 regs; xsc transposed [li][68] -> inner loop = 16 b128 broadcasts.
__global__ __launch_bounds__(256, 4) void k2(
    const float* __restrict__ Ws_, const float* __restrict__ gv, const float* __restrict__ bev,
    const float* __restrict__ gt, const float* __restrict__ bet,
    float* __restrict__ ws)
{
  __shared__ float xsc2[82*68];
  __shared__ float accs[128];
  __shared__ float bnp[4];
  __shared__ float pr[4][4];
  int tid = threadIdx.x;
  int n = blockIdx.x >> 2;
  int chunk = blockIdx.x & 3;
  int l0 = chunk * 82;
  int cw = (325 - l0 < 82) ? (325 - l0) : 82;
  // reduce per-block BN partials (4096 x float4)
  {
    float4 acc = {0.f,0.f,0.f,0.f};
    const float4* p4 = (const float4*)&ws[WS_P1B];
    for (int b = tid; b < 4096; b += 256){
      float4 v = p4[b];
      acc.x += v.x; acc.y += v.y; acc.z += v.z; acc.w += v.w;
    }
    #pragma unroll
    for (int off = 32; off >= 1; off >>= 1){
      acc.x += __shfl_xor(acc.x, off); acc.y += __shfl_xor(acc.y, off);
      acc.z += __shfl_xor(acc.z, off); acc.w += __shfl_xor(acc.w, off);
    }
    int lane = tid & 63, wv = tid >> 6;
    if (lane == 0){ pr[wv][0] = acc.x; pr[wv][1] = acc.y; pr[wv][2] = acc.z; pr[wv][3] = acc.w; }
  }
  int o = tid & 63;
  float4 wreg[16];
  {
    const float4* wsp = (const float4*)(Ws_ + o*64);
    #pragma unroll
    for (int k = 0; k < 16; k++) wreg[k] = wsp[k];
  }
  if (tid < 128) accs[tid] = 0.f;
  __syncthreads();
  if (tid == 0){
    float p0 = pr[0][0]+pr[1][0]+pr[2][0]+pr[3][0];
    float p1 = pr[0][1]+pr[1][1]+pr[2][1]+pr[3][1];
    float p2 = pr[0][2]+pr[1][2]+pr[2][2]+pr[3][2];
    float p3 = pr[0][3]+pr[1][3]+pr[2][3]+pr[3][3];
    float Mv = 1228800.f;
    float mv = p0 / Mv;
    float varv = p1 / Mv - mv*mv;
    float av = gv[0] * rsqrtf(varv + EPSF);
    bnp[0] = av; bnp[1] = bev[0] - mv*av;
    float Mt = 102400.f;
    float mt = p2 / Mt;
    float vart = p3 / Mt - mt*mt;
    float at = gt[0] * rsqrtf(vart + EPSF);
    bnp[2] = at; bnp[3] = bet[0] - mt*at;
  }
  __syncthreads();
  float a_v = bnp[0], b_v = bnp[1], a_t = bnp[2], b_t = bnp[3];
  for (int i = tid; i < 64*cw; i += 256){
    int ch = i / cw, li = i - ch*cw;
    int f = ch*325 + l0 + li;
    float e;
    if (f < 1600) e = ws[WS_XT + n*1600 + f] * a_t + b_t;
    else          e = ws[WS_XV + n*19200 + (f - 1600)] * a_v + b_v;
    xsc2[li*68 + ch] = hswish(e);
  }
  __syncthreads();
  float s1 = 0.f, s2 = 0.f;
  for (int i = tid; i < 64*cw; i += 256){
    int li = i >> 6;
    const float4* xp = (const float4*)&xsc2[li*68];
    float acc = 0.f;
    #pragma unroll
    for (int k = 0; k < 16; k++){
      float4 w = wreg[k];
      float4 x = xp[k];
      acc += w.x*x.x + w.y*x.y + w.z*x.z + w.w*x.w;
    }
    ws[WS_XS + (n*64 + o)*325 + l0 + li] = acc;
    s1 += acc; s2 += acc*acc;
  }
  atomicAdd(&accs[o*2+0], s1);
  atomicAdd(&accs[o*2+1], s2);
  __syncthreads();
  if (tid < 128) ws[WS_A2B + blockIdx.x*128 + tid] = accs[tid];
}

// K3p: grid (82,8). Block reduces A2B for its 1-2 d's -> BN params; partial n-sum
// of hswish(bn(xs)) over 8 n's -> WS_SP[ny][20800]. No atomics, no zero-kernel.
__global__ __launch_bounds__(256) void k3p(const float* __restrict__ gs, const float* __restrict__ bes,
                                           float* __restrict__ ws)
{
  __shared__ float red[16];
  __shared__ float aab[4];
  int tid = threadIdx.x;
  int i0 = blockIdx.x*256;
  int ny = blockIdx.y;
  int d0 = i0 / 325;
  int d1 = (i0 + 255) / 325; if (d1 > 63) d1 = 63;
  float p0 = ws[WS_A2B + tid*128 + d0*2];
  float p1 = ws[WS_A2B + tid*128 + d0*2 + 1];
  float p2 = ws[WS_A2B + tid*128 + d1*2];
  float p3 = ws[WS_A2B + tid*128 + d1*2 + 1];
  #pragma unroll
  for (int off = 32; off >= 1; off >>= 1){
    p0 += __shfl_xor(p0, off); p1 += __shfl_xor(p1, off);
    p2 += __shfl_xor(p2, off); p3 += __shfl_xor(p3, off);
  }
  int lane = tid & 63, wv = tid >> 6;
  if (lane == 0){ red[wv*4+0]=p0; red[wv*4+1]=p1; red[wv*4+2]=p2; red[wv*4+3]=p3; }
  __syncthreads();
  if (tid == 0){
    float s1 = red[0]+red[4]+red[8]+red[12];
    float s2 = red[1]+red[5]+red[9]+red[13];
    float m = s1 / 20800.f;
    float var = s2 / 20800.f - m*m;
    float a = gs[d0] * rsqrtf(var + EPSF);
    aab[0] = a; aab[1] = bes[d0] - m*a;
    s1 = red[2]+red[6]+red[10]+red[14];
    s2 = red[3]+red[7]+red[11]+red[15];
    m = s1 / 20800.f;
    var = s2 / 20800.f - m*m;
    a = gs[d1] * rsqrtf(var + EPSF);
    aab[2] = a; aab[3] = bes[d1] - m*a;
  }
  __syncthreads();
  int i = i0 + tid;
  if (i < 20800){
    int dch = i / 325;
    float a = (dch == d0) ? aab[0] : aab[2];
    float b = (dch == d0) ? aab[1] : aab[3];
    const float* base = ws + WS_XS + ny*8*20800 + i;
    float sum = 0.f;
    #pragma unroll
    for (int k = 0; k < 8; k++)
      sum += hswish(a * base[k*20800] + b);
    ws[WS_SP + ny*20800 + i] = sum;
  }
}

// K4r: reduce 8 partial slices -> WS_S.
__global__ __launch_bounds__(256) void k4r(float* __restrict__ ws)
{
  int i = blockIdx.x*256 + threadIdx.x;
  if (i >= 20800) return;
  float s = 0.f;
  #pragma unroll
  for (int k = 0; k < 8; k++) s += ws[WS_SP + k*20800 + i];
  ws[WS_S + i] = s;
}

// K4: x_time out + gate (R5-proven structure, 82 blocks).
__global__ __launch_bounds__(256) void k4(const float* __restrict__ Wt2, const float* __restrict__ bt2,
    const float* __restrict__ Wv2, const float* __restrict__ bv2,
    float* __restrict__ out2, float* __restrict__ ws)
{
  int i = blockIdx.x*256 + threadIdx.x;
  if (i < 19200){
    int o = i / 300, t = i - o*300;
    float acc = 0.f;
    #pragma unroll 8
    for (int dd = 0; dd < 64; dd++)
      acc += Wt2[o*64+dd] * ws[WS_S + dd*325 + t];
    out2[i] = sigm(acc * (1.f/64.f) + bt2[o]);
  } else if (i < 20800){
    int g = i - 19200;
    int v = g >> 6, cc = g & 63;
    float acc = 0.f;
    #pragma unroll 8
    for (int dd = 0; dd < 64; dd++)
      acc += Wv2[cc*64+dd] * ws[WS_S + dd*325 + 300 + v];
    ws[WS_GATE + v*64 + cc] = tanhf(sigm(acc * (1.f/64.f) + bv2[cc])) + 1.f;
  }
}

// K5y: single GEMM pass: stats (reg accumulators -> colacc -> private partials)
// AND (if storeY) writes rotated bf16 y to WS_YWS (3750 u32/row) via in-LDS scatter.
__global__ __launch_bounds__(512, 2) void k5y(const float* __restrict__ x0,
    const float* __restrict__ Lw, float* __restrict__ ws, const int storeY)
{
  __shared__ u16 xraw[64*154];
  __shared__ u16 zsh[160*72];
  __shared__ u16 lwt[64*72];
  __shared__ float gate[1600];
  __shared__ float colacc[3300];
  int tid = threadIdx.x;
  int n = blockIdx.x >> 3, e8 = blockIdx.x & 7;
  int c0 = (e8*50) >> 3, c1 = ((e8+1)*50) >> 3;   // 6 or 7 chunks of 6 t-steps
  const float2* xsrc = (const float2*)x0;
  u32* yws = (u32*)(ws + WS_YWS);

  for (int i = tid; i < 1600; i += 512) gate[i] = ws[WS_GATE + i];
  for (int i = tid; i < 4096; i += 512){
    int c = i >> 6, d = i & 63;                    // coalesced Lw read
    lwt[d*72 + c] = f2us(Lw[c*64 + d]);
  }
  for (int i = tid; i < 3300; i += 512) colacc[i] = 0.f;
  for (int i = tid; i < 640; i += 512){ int c = i & 63, r = 150 + (i >> 6); zsh[r*72 + c] = 0; }
  // stage first chunk
  for (int i = tid; i < 4800; i += 512){
    int c = i / 75, j = i - c*75;
    float2 xy = xsrc[(n*64 + c)*3750 + c0*75 + j];
    *(u32*)&xraw[c*154 + 2*j] = (u32)f2us(xy.x) | ((u32)f2us(xy.y) << 16);
  }

  // --- chunk-invariant gather slots (pairs of adjacent c): packed src + gate offset ---
  u32 gsrc[10]; int gadr[10];
  #pragma unroll
  for (int k = 0; k < 10; k++){
    int p = tid + k*512;
    if (k < 9 || p < 4800){
      int cp = (p & 31)*2, r = p >> 5;
      int v = r - 25*((r*41) >> 10);                // r % 25, r < 160
      int base = r - v;
      int w = v + cp;
      int u1 = w - 25*((w*41) >> 10);               // (v+cp) % 25, w < 88
      int w2 = w + 1;
      int u2 = w2 - 25*((w2*41) >> 10);
      gsrc[k] = (u32)(cp*154 + base + u1) | ((u32)((cp+1)*154 + base + u2) << 16);
      gadr[k] = v*64 + cp;
    }
  }

  int lane = tid & 63, wvi = tid >> 6;
  int m16 = lane & 15, kq = lane >> 4;
  int dd = (wvi & 3)*16 + m16;

  // --- chunk-invariant scatter slots: xraw idx (0xFFFF sentinel for pad rows) ---
  u32 eidx[20];
  #pragma unroll
  for (int it = 0; it < 5; it++){
    int T = wvi + it*8;
    int r0 = (T >> 2) * 16;
    #pragma unroll
    for (int q = 0; q < 4; q++){
      int r = r0 + kq*4 + q;
      u32 e = 0xFFFFu;
      if (r < 150){
        int v = r - 25*((r*41) >> 10);
        int w = v + dd;
        int u = w - 25*((w*41) >> 10);
        e = (u32)(dd*154 + (r - v) + u);
      }
      eidx[it*4 + q] = e;
    }
  }

  bf16x8 b0, b1;
  float s_acc[20], q_acc[20];
  #pragma unroll
  for (int z = 0; z < 20; z++){ s_acc[z] = 0.f; q_acc[z] = 0.f; }

  for (int cc = c0; cc < c1; cc++){
    __syncthreads();                                // xraw ready
    #pragma unroll
    for (int k = 0; k < 10; k++){
      if (k < 9 || tid < 192){
        int p = tid + k*512;
        int dst = (p >> 5)*72 + (p & 31)*2;
        float gA = gate[gadr[k]];
        float gB = gate[gadr[k] + 1];
        u16 x1 = xraw[gsrc[k] & 0xFFFFu];
        u16 x2 = xraw[gsrc[k] >> 16];
        u32 pk = (u32)f2us(us2f(x1)*gA) | ((u32)f2us(us2f(x2)*gB) << 16);
        *(u32*)&zsh[dst] = pk;
      }
    }
    __syncthreads();                                // zsh ready, xraw gather-reads done
    if (cc == c0){
      b0 = *(const bf16x8*)&lwt[dd*72 + kq*8];
      b1 = *(const bf16x8*)&lwt[dd*72 + 32 + kq*8];
    }
    // prefetch next chunk into regs
    float2 pf[10];
    bool has = (cc + 1 < c1);
    if (has){
      #pragma unroll
      for (int k = 0; k < 10; k++){
        int i = tid + k*512;
        if (i < 4800){
          int c = i / 75, j = i - c*75;
          pf[k] = xsrc[(n*64 + c)*3750 + (cc+1)*75 + j];
        }
      }
    }
    f32x4 acc[5];
    #pragma unroll
    for (int it = 0; it < 5; it++){
      int T = wvi + it*8;
      int r0 = (T >> 2) * 16;
      bf16x8 a0 = *(const bf16x8*)&zsh[(r0 + m16)*72 + kq*8];
      bf16x8 a1 = *(const bf16x8*)&zsh[(r0 + m16)*72 + 32 + kq*8];
      f32x4 a = {0.f,0.f,0.f,0.f};
      a = __builtin_amdgcn_mfma_f32_16x16x32_bf16(a0, b0, a, 0, 0, 0);
      a = __builtin_amdgcn_mfma_f32_16x16x32_bf16(a1, b1, a, 0, 0, 0);
      acc[it] = a;
      // stats: pad rows contribute exactly 0
      #pragma unroll
      for (int q = 0; q < 4; q++){
        float y = a[q];
        s_acc[it*4 + q] += y;
        q_acc[it*4 + q] += y*y;
      }
    }
    if (storeY){
      // scatter rotated y into xraw (input no longer needed this chunk)
      #pragma unroll
      for (int s = 0; s < 20; s++){
        u32 e = eidx[s];
        if (e != 0xFFFFu) xraw[e] = f2us(acc[s>>2][s&3]);
      }
      __syncthreads();                              // scatter done
      for (int i = tid; i < 4800; i += 512){
        int d = i / 75, j = i - d*75;
        yws[(n*64 + d)*3750 + cc*75 + j] = *(const u32*)&xraw[d*154 + 2*j];
      }
    }
    __syncthreads();                                // xraw free for prefetch write
    if (has){
      #pragma unroll
      for (int k = 0; k < 10; k++){
        int i = tid + k*512;
        if (i < 4800){
          int c = i / 75, j = i - c*75;
          *(u32*)&xraw[c*154 + 2*j] = (u32)f2us(pf[k].x) | ((u32)f2us(pf[k].y) << 16);
        }
      }
    }
  }
  // one-time flush of register accumulators into LDS
  #pragma unroll
  for (int it = 0; it < 5; it++){
    int T = wvi + it*8;
    int r0 = (T >> 2) * 16;
    #pragma unroll
    for (int q = 0; q < 4; q++){
      int r = r0 + kq*4 + q;
      if (r < 150){
        int v = r - 25*((r*41) >> 10);              // r % 25, valid r<160
        atomicAdd(&colacc[v*66 + dd], s_acc[it*4 + q]);
        atomicAdd(&colacc[1650 + v*66 + dd], q_acc[it*4 + q]);
      }
    }
  }
  __syncthreads();
  // non-atomic private partial slice (coalesced)
  float* dst = ws + WS_PARTIAL + blockIdx.x*3200;
  for (int i = tid; i < 3200; i += 512){
    int f = (i < 1600) ? i : (i - 1600);
    int v = f >> 6, d = f & 63;
    dst[i] = colacc[((i < 1600) ? 0 : 1650) + v*66 + d];
  }
}

// K5ab: reduce 512 partial slices AND fold gbn/bbn into per-column affine a,b.
// 25 blocks; block b owns f = b*64 + (0..63), i.e. v = b, d = 0..63.
// rot=1: store at rotated column (vi*64+d) for streaming k6n; rot=0: at v*64+d for fallback k6.
__global__ __launch_bounds__(256) void k5ab(const float* __restrict__ gbn, const float* __restrict__ bbn,
                                            float* __restrict__ ws, const int rot)
{
  __shared__ float rs[4][64];
  __shared__ float rq[4][64];
  int tid = threadIdx.x;
  int fo = tid & 63, g = tid >> 6;
  int f = blockIdx.x*64 + fo;
  const float* src = ws + WS_PARTIAL;
  float s = 0.f, q = 0.f;
  #pragma unroll 8
  for (int b = g*128; b < g*128 + 128; ++b){
    s += src[b*3200 + f];
    q += src[b*3200 + 1600 + f];
  }
  rs[g][fo] = s; rq[g][fo] = q;
  __syncthreads();
  if (tid < 64){
    int d = tid, v = blockIdx.x;
    float S = rs[0][d] + rs[1][d] + rs[2][d] + rs[3][d];
    float Q = rq[0][d] + rq[1][d] + rq[2][d] + rq[3][d];
    float m = S / 19200.f;
    float var = Q / 19200.f - m*m;
    float rsq = rsqrtf(var + EPSF);
    int vi = (v + d) % 25;
    int fi = vi*64 + d;
    float a = gbn[fi] * rsq;
    int o = rot ? (vi*64 + d) : (v*64 + d);
    ws[WS_ABN + o] = a;
    ws[WS_BBN + o] = bbn[fi] - m*a;
  }
}

// K6n: streaming finale: out = relu(bf16(y)*A[u,d] + B[u,d] + x0). 4096 blocks = (n,d) rows.
// float4/uint2 vectorized; u-index incremental (1024 = -1 mod 25), no runtime div in loop.
__global__ __launch_bounds__(256) void k6n(const float* __restrict__ x0,
    float* __restrict__ out, const float* __restrict__ ws)
{
  __shared__ float sA2[28];
  __shared__ float sB2[28];
  int row = blockIdx.x;                             // n*64 + d
  int d = row & 63;
  int tid = threadIdx.x;
  if (tid < 28){
    int um = (tid >= 25) ? (tid - 25) : tid;
    sA2[tid] = ws[WS_ABN + um*64 + d];
    sB2[tid] = ws[WS_BBN + um*64 + d];
  }
  __syncthreads();
  const uint2*  yrow = (const uint2*)((const u32*)(ws + WS_YWS) + row*3750);
  const float4* xrow = (const float4*)x0 + row*1875;
  float4*       orow = (float4*)out + row*1875;
  int u = (4*tid) % 25;
  for (int j = tid; j < 1875; j += 256){
    uint2 yp = yrow[j];
    float4 x = xrow[j];
    float4 o;
    o.x = fmaxf(us2f((u16)(yp.x & 0xFFFFu)) * sA2[u]   + sB2[u]   + x.x, 0.f);
    o.y = fmaxf(us2f((u16)(yp.x >> 16))     * sA2[u+1] + sB2[u+1] + x.y, 0.f);
    o.z = fmaxf(us2f((u16)(yp.y & 0xFFFFu)) * sA2[u+2] + sB2[u+2] + x.z, 0.f);
    o.w = fmaxf(us2f((u16)(yp.y >> 16))     * sA2[u+3] + sB2[u+3] + x.w, 0.f);
    orow[j] = o;
    u = (u == 0) ? 24 : (u - 1);                    // +1024 elems = -1 mod 25
  }
}

// K6 (fallback, only if workspace too small for y-store): GEMM apply pass.
__global__ __launch_bounds__(512, 2) void k6(const float* __restrict__ x0,
    const float* __restrict__ Lw, float* __restrict__ out, float* __restrict__ ws)
{
  __shared__ u16 xraw[64*154];
  __shared__ u16 zsh[160*72];
  __shared__ u16 lwt[64*72];
  __shared__ float gate[1600];
  __shared__ float affA[1650];
  __shared__ float affB[1650];
  int tid = threadIdx.x;
  int n = blockIdx.x >> 3, e8 = blockIdx.x & 7;
  int c0 = (e8*50) >> 3, c1 = ((e8+1)*50) >> 3;
  const float2* xsrc = (const float2*)x0;

  for (int i = tid; i < 1600; i += 512){
    gate[i] = ws[WS_GATE + i];
    int v = i >> 6, d = i & 63;
    affA[v*66 + d] = ws[WS_ABN + i];
    affB[v*66 + d] = ws[WS_BBN + i];
  }
  for (int i = tid; i < 4096; i += 512){
    int c = i >> 6, d = i & 63;
    lwt[d*72 + c] = f2us(Lw[c*64 + d]);
  }
  for (int i = tid; i < 640; i += 512){ int c = i & 63, r = 150 + (i >> 6); zsh[r*72 + c] = 0; }
  for (int i = tid; i < 4800; i += 512){
    int c = i / 75, j = i - c*75;
    float2 xy = xsrc[(n*64 + c)*3750 + c0*75 + j];
    *(u32*)&xraw[c*154 + 2*j] = (u32)f2us(xy.x) | ((u32)f2us(xy.y) << 16);
  }

  u32 gsrc[10]; int gadr[10];
  #pragma unroll
  for (int k = 0; k < 10; k++){
    int p = tid + k*512;
    if (k < 9 || p < 4800){
      int cp = (p & 31)*2, r = p >> 5;
      int v = r - 25*((r*41) >> 10);
      int base = r - v;
      int w = v + cp;
      int u1 = w - 25*((w*41) >> 10);
      int w2 = w + 1;
      int u2 = w2 - 25*((w2*41) >> 10);
      gsrc[k] = (u32)(cp*154 + base + u1) | ((u32)((cp+1)*154 + base + u2) << 16);
      gadr[k] = v*64 + cp;
    }
  }

  int lane = tid & 63, wvi = tid >> 6;
  int m16 = lane & 15, kq = lane >> 4;
  int dd = (wvi & 3)*16 + m16;

  u32 eidx[20];
  #pragma unroll
  for (int it = 0; it < 5; it++){
    int T = wvi + it*8;
    int r0 = (T >> 2) * 16;
    #pragma unroll
    for (int q = 0; q < 4; q++){
      int r = r0 + kq*4 + q;
      u32 e = 0xFFFFu;
      if (r < 150){
        int v = r - 25*((r*41) >> 10);
        int w = v + dd;
        int u = w - 25*((w*41) >> 10);
        e = (u32)(dd*154 + (r - v) + u) | ((u32)(v*66 + dd) << 16);
      }
      eidx[it*4 + q] = e;
    }
  }

  bf16x8 b0, b1;

  for (int cc = c0; cc < c1; cc++){
    __syncthreads();
    #pragma unroll
    for (int k = 0; k < 10; k++){
      if (k < 9 || tid < 192){
        int p = tid + k*512;
        int dst = (p >> 5)*72 + (p & 31)*2;
        float gA = gate[gadr[k]];
        float gB = gate[gadr[k] + 1];
        u16 x1 = xraw[gsrc[k] & 0xFFFFu];
        u16 x2 = xraw[gsrc[k] >> 16];
        u32 pk = (u32)f2us(us2f(x1)*gA) | ((u32)f2us(us2f(x2)*gB) << 16);
        *(u32*)&zsh[dst] = pk;
      }
    }
    __syncthreads();
    if (cc == c0){
      b0 = *(const bf16x8*)&lwt[dd*72 + kq*8];
      b1 = *(const bf16x8*)&lwt[dd*72 + 32 + kq*8];
    }
    float2 pf[10];
    bool has = (cc + 1 < c1);
    if (has){
      #pragma unroll
      for (int k = 0; k < 10; k++){
        int i = tid + k*512;
        if (i < 4800){
          int c = i / 75, j = i - c*75;
          pf[k] = xsrc[(n*64 + c)*3750 + (cc+1)*75 + j];
        }
      }
    }
    f32x4 acc[5];
    #pragma unroll
    for (int it = 0; it < 5; it++){
      int T = wvi + it*8;
      int r0 = (T >> 2) * 16;
      bf16x8 a0 = *(const bf16x8*)&zsh[(r0 + m16)*72 + kq*8];
      bf16x8 a1 = *(const bf16x8*)&zsh[(r0 + m16)*72 + 32 + kq*8];
      f32x4 a = {0.f,0.f,0.f,0.f};
      a = __builtin_amdgcn_mfma_f32_16x16x32_bf16(a0, b0, a, 0, 0, 0);
      a = __builtin_amdgcn_mfma_f32_16x16x32_bf16(a1, b1, a, 0, 0, 0);
      acc[it] = a;
    }
    #pragma unroll
    for (int s = 0; s < 20; s++){
      u32 e = eidx[s];
      if ((e & 0xFFFFu) != 0xFFFFu){
        int idx = (int)(e & 0xFFFFu), ao = (int)(e >> 16);
        float resid = us2f(xraw[idx]);
        float val = acc[s>>2][s&3] * affA[ao] + affB[ao] + resid;
        xraw[idx] = f2us(fmaxf(val, 0.f));
      }
    }
    __syncthreads();
    for (int i = tid; i < 4800; i += 512){
      int d = i / 75, j = i - d*75;
      u32 pk = *(const u32*)&xraw[d*154 + 2*j];
      float2 o; o.x = us2f((u16)(pk & 0xFFFFu)); o.y = us2f((u16)(pk >> 16));
      ((float2*)out)[(n*64 + d)*3750 + cc*75 + j] = o;
    }
    __syncthreads();
    if (has){
      #pragma unroll
      for (int k = 0; k < 10; k++){
        int i = tid + k*512;
        if (i < 4800){
          int c = i / 75, j = i - c*75;
          *(u32*)&xraw[c*154 + 2*j] = (u32)f2us(pf[k].x) | ((u32)f2us(pf[k].y) << 16);
        }
      }
    }
  }
}

extern "C" void kernel_launch(void* const* d_in, const int* in_sizes, int n_in,
                              void* d_out, int out_size, void* d_ws, size_t ws_size,
                              hipStream_t stream)
{
  const float* x0  = (const float*)d_in[0];
  // d_in[1] shift_in, d_in[2] shift_out: closed-form rotations used instead
  const float* Wv  = (const float*)d_in[3];
  const float* bv  = (const float*)d_in[4];
  const float* gv  = (const float*)d_in[5];
  const float* bev = (const float*)d_in[6];
  const float* Wt  = (const float*)d_in[7];
  const float* bt  = (const float*)d_in[8];
  const float* gt  = (const float*)d_in[9];
  const float* bet = (const float*)d_in[10];
  const float* Ws_ = (const float*)d_in[11];
  // d_in[12] bs: cancels exactly in BN — dropped
  const float* gs  = (const float*)d_in[13];
  const float* bes = (const float*)d_in[14];
  const float* Wv2 = (const float*)d_in[15];
  const float* bv2 = (const float*)d_in[16];
  const float* Wt2 = (const float*)d_in[17];
  const float* bt2 = (const float*)d_in[18];
  const float* Lw  = (const float*)d_in[19];
  // d_in[20] Lb: cancels exactly in final BN — dropped
  const float* gbn = (const float*)d_in[21];
  const float* bbn = (const float*)d_in[22];
  float* out = (float*)d_out;
  float* ws = (float*)d_ws;

  const int big = (ws_size >= (size_t)(WS_YWS + 15360000) * 4) ? 1 : 0;

  k1<<<dim3(4096), dim3(256), 0, stream>>>(x0, Wv, bv, Wt, bt, ws);
  k2<<<dim3(256), dim3(256), 0, stream>>>(Ws_, gv, bev, gt, bet, ws);
  k3p<<<dim3(82, 8), dim3(256), 0, stream>>>(gs, bes, ws);
  k4r<<<dim3(82), dim3(256), 0, stream>>>(ws);
  k4<<<dim3(82), dim3(256), 0, stream>>>(Wt2, bt2, Wv2, bv2, out + 30720000, ws);
  k5y<<<dim3(512), dim3(512), 0, stream>>>(x0, Lw, ws, big);
  k5ab<<<dim3(25), dim3(256), 0, stream>>>(gbn, bbn, ws, big);
  if (big){
    k6n<<<dim3(4096), dim3(256), 0, stream>>>(x0, out, ws);
  } else {
    k6<<<dim3(512), dim3(512), 0, stream>>>(x0, Lw, out, ws);
  }
}